// Round 9
// baseline (128.162 us; speedup 1.0000x reference)
//
#include <hip/hip_runtime.h>
#include <stdint.h>

// ColBERT MaxSim on MI355X (gfx950), round 9.
// scores[b,c] = sum_n max_s dot(qs[b,n,:], ps[c,s,:])
// qs: (64, 32, 128) f32, ps: (64, 1024, 128) f32, out: (64, 64) f32.
//
// R8 ledger: VGPR=120 + no scratch traffic => compiler parked the pinned
// qfr[32] uint4 in AGPRs; unified demand ~280 regs -> 1 wave/SIMD -> occupancy
// collapse (16.5%), 4 CU-rounds, MFMA floor (13.8 us) exposed at 28.5% util of
// 44.3 us. The 32x32x16 shape cannot fit Q(128) + acc(16/chain) in 256 regs.
// R9: switch to mfma_f32_16x16x32_bf16 (acc = 4 regs/chain). Per 16-row
// s-tile: 4 A-frag loads feed 32 MFMAs (4 b x 2 n-halves x 4 k-steps) = 1:8.
// Honest tally: qf 128 + A dbuf 32 + acc 32 + misc ~= 220 < 256 -> true
// 2 waves/SIMD under launch_bounds(256,2). Q loaded once from global, pinned.

typedef __bf16 bf16x8 __attribute__((ext_vector_type(8)));
typedef float floatx4 __attribute__((ext_vector_type(4)));

#define QS_N (64u * 32u * 128u)    // 262144
#define PS_N (64u * 1024u * 128u)  // 8388608

__device__ inline unsigned short f2bf(float f) {
  union { float f; uint32_t u; } x{f};
  uint32_t r = (x.u + 0x7FFFu + ((x.u >> 16) & 1u)) >> 16;  // RNE
  return (unsigned short)r;
}

// Fused cvt: first QS_N/4 float4s from qs, rest from ps; qsb = ws, psb = ws + QS_N.
__global__ __launch_bounds__(256) void cvt_kernel(const float* __restrict__ qs,
                                                  const float* __restrict__ ps,
                                                  ushort* __restrict__ outb) {
  const int nq4 = QS_N / 4;
  const int n4 = (QS_N + PS_N) / 4;
  int i = blockIdx.x * 256 + threadIdx.x;
  if (i >= n4) return;
  float4 f;
  if (i < nq4) {
    f = ((const float4*)qs)[i];
  } else {
    f = ((const float4*)ps)[i - nq4];
  }
  ushort4 o;
  o.x = f2bf(f.x); o.y = f2bf(f.y); o.z = f2bf(f.z); o.w = f2bf(f.w);
  ((ushort4*)outb)[i] = o;
}

union FragU { uint4 u; bf16x8 v; };

__device__ inline bf16x8 as_frag(uint4 u) {
  FragU x;
  x.u = u;
  return x.v;
}

// Load 8 bf16 (16 B) as uint4, from pre-converted bf16 or on-the-fly from f32.
template <bool PRECVT>
__device__ inline uint4 load16(const void* p, int off) {
  if (PRECVT) {
    return *(const uint4*)((const ushort*)p + off);
  } else {
    const float* q = (const float*)p + off;
    float4 x = *(const float4*)q;
    float4 y = *(const float4*)(q + 4);
    union { ushort s[8]; uint4 u; } r;
    r.s[0] = f2bf(x.x); r.s[1] = f2bf(x.y); r.s[2] = f2bf(x.z); r.s[3] = f2bf(x.w);
    r.s[4] = f2bf(y.x); r.s[5] = f2bf(y.y); r.s[6] = f2bf(y.z); r.s[7] = f2bf(y.w);
    return r.u;
  }
}

#define ZERO4 {0, 0, 0, 0}

// One 16-row s-tile vs 4 query blocks x 2 n-halves: 32 MFMAs, 8 acc chains
// (4 regs each), 4 k-steps. A-frags in ABUF[0..3] (one per k-step).
#define TILE_COMPUTE(ABUF)                                                      \
  {                                                                             \
    floatx4 acc[4][2];                                                          \
    _Pragma("unroll") for (int b = 0; b < 4; ++b)                               \
      _Pragma("unroll") for (int h = 0; h < 2; ++h)                             \
        acc[b][h] = (floatx4)ZERO4;                                             \
    _Pragma("unroll") for (int k2 = 0; k2 < 4; ++k2) {                          \
      bf16x8 af = as_frag(ABUF[k2]);                                            \
      _Pragma("unroll") for (int b = 0; b < 4; ++b)                             \
        _Pragma("unroll") for (int h = 0; h < 2; ++h)                           \
          acc[b][h] = __builtin_amdgcn_mfma_f32_16x16x32_bf16(                  \
              af, as_frag(qfr[b][h][k2]), acc[b][h], 0, 0, 0);                  \
    }                                                                           \
    _Pragma("unroll") for (int b = 0; b < 4; ++b)                               \
      _Pragma("unroll") for (int h = 0; h < 2; ++h) {                           \
        float m = fmaxf(fmaxf(acc[b][h][0], acc[b][h][1]),                      \
                        fmaxf(acc[b][h][2], acc[b][h][3]));                     \
        vmax[b][h] = fmaxf(vmax[b][h], m);                                      \
      }                                                                         \
  }

template <bool PRECVT>
__global__ __launch_bounds__(256, 2) void maxsim_kernel(const void* __restrict__ qsv,
                                                        const void* __restrict__ psv,
                                                        float* __restrict__ out) {
  const int lane = threadIdx.x & 63;
  const int wave = threadIdx.x >> 6;

  // XCD-aware swizzle (R4: keeps P_c L2-resident, FETCH 66 -> 10 MB).
  const int xcd = blockIdx.x & 7;
  const int slot = blockIdx.x >> 3;
  const int c = xcd * 8 + (slot >> 4);
  const int bg = slot & 15;
  const int b0 = bg * 4;

  // 16x16x32 fragment lane pattern: idx16 = lane&15 (A: s-row, B: q-token),
  // koff = (lane>>4)*8; k-step k2 adds k2*32.
  const int idx16 = lane & 15;
  const int koff = (lane >> 4) * 8;

  // Q fragments: 4 b x 2 n-halves x 4 k-steps = 32 x 16 B = 128 VGPRs.
  // Loaded from global ONCE, pinned per 32-bit component (opaque to remat).
  uint4 qfr[4][2][4];
#pragma unroll
  for (int b = 0; b < 4; ++b)
#pragma unroll
    for (int h = 0; h < 2; ++h)
#pragma unroll
      for (int k2 = 0; k2 < 4; ++k2) {
        const int goff = ((b0 + b) * 32 + h * 16 + idx16) * 128 + k2 * 32 + koff;
        uint4 v = load16<PRECVT>(qsv, goff);
        asm volatile("" : "+v"(v.x), "+v"(v.y), "+v"(v.z), "+v"(v.w));
        qfr[b][h][k2] = v;
      }

  // Wave covers s in [wave*256, wave*256+256): 16 tiles of 16 doc tokens.
  const int pbase = (c * 1024 + wave * 256 + idx16) * 128 + koff;

  // Tile-0 A prefetch (4 x 16 B).
  uint4 a0[4], a1[4];
#pragma unroll
  for (int k2 = 0; k2 < 4; ++k2) a0[k2] = load16<PRECVT>(psv, pbase + k2 * 32);

  float vmax[4][2];
#pragma unroll
  for (int b = 0; b < 4; ++b) {
    vmax[b][0] = -3.4e38f;
    vmax[b][1] = -3.4e38f;
  }

#pragma unroll 1
  for (int t = 0; t < 16; t += 2) {
    // Prefetch tile t+1 into a1; compute tile t from a0.
#pragma unroll
    for (int k2 = 0; k2 < 4; ++k2)
      a1[k2] = load16<PRECVT>(psv, pbase + (t + 1) * 2048 + k2 * 32);
    TILE_COMPUTE(a0)
    // Prefetch tile t+2 into a0 (wrap on last iter; harmless re-read).
    int t2 = t + 2;
    if (t2 > 15) t2 = 0;
#pragma unroll
    for (int k2 = 0; k2 < 4; ++k2)
      a0[k2] = load16<PRECVT>(psv, pbase + t2 * 2048 + k2 * 32);
    // Compute tile t+1 from a1.
    TILE_COMPUTE(a1)
  }

  // C/D: col = lane&15 (q-token), row = (lane>>4)*4 + reg (s). The 4 lane-quads
  // hold disjoint s-rows: fold with xor 16 and 32 so all lanes with equal
  // (lane&15) share the max over the full tile set.
#pragma unroll
  for (int b = 0; b < 4; ++b)
#pragma unroll
    for (int h = 0; h < 2; ++h) {
      float v = vmax[b][h];
      v = fmaxf(v, __shfl_xor(v, 16, 64));
      v = fmaxf(v, __shfl_xor(v, 32, 64));
      vmax[b][h] = v;
    }

  // Cross-wave max, then sum over the 32 query tokens.
  __shared__ float red[4][4][32];  // [wave][b][n]
  if (lane < 16) {
#pragma unroll
    for (int b = 0; b < 4; ++b) {
      red[wave][b][lane] = vmax[b][0];
      red[wave][b][16 + lane] = vmax[b][1];
    }
  }
  __syncthreads();
  if (threadIdx.x < 128) {
    const int b = threadIdx.x >> 5;
    const int n = threadIdx.x & 31;
    float m = fmaxf(fmaxf(red[0][b][n], red[1][b][n]), fmaxf(red[2][b][n], red[3][b][n]));
#pragma unroll
    for (int o = 16; o > 0; o >>= 1) m += __shfl_xor(m, o, 32);
    if (n == 0) out[(b0 + b) * 64 + c] = m;
  }
}

extern "C" void kernel_launch(void* const* d_in, const int* in_sizes, int n_in,
                              void* d_out, int out_size, void* d_ws, size_t ws_size,
                              hipStream_t stream) {
  const float* qs = (const float*)d_in[0];
  const float* ps = (const float*)d_in[1];
  float* out = (float*)d_out;

  const size_t need = (QS_N + PS_N) * sizeof(ushort);  // 16.5 MiB

  if (ws_size >= need) {
    ushort* wsb = (ushort*)d_ws;
    const int n4 = (int)((QS_N + PS_N) / 4);
    cvt_kernel<<<(n4 + 255) / 256, 256, 0, stream>>>(qs, ps, wsb);
    maxsim_kernel<true><<<dim3(64 * 16), dim3(256), 0, stream>>>(wsb, wsb + QS_N, out);
  } else {
    maxsim_kernel<false><<<dim3(64 * 16), dim3(256), 0, stream>>>(qs, ps, out);
  }
}